// Round 4
// baseline (2735.192 us; speedup 1.0000x reference)
//
#include <hip/hip_runtime.h>

#define B_ 32
#define T_ 24
#define N_ 2048
#define D_ 64
#define K_ 32
#define H_ 16
#define NB 16

typedef __attribute__((ext_vector_type(8))) short bf16x8;
typedef __attribute__((ext_vector_type(4))) float f32x4;

__device__ __forceinline__ unsigned short f2bf(float f) {
    unsigned int u = __float_as_uint(f);
    return (unsigned short)((u + 0x7FFFu + ((u >> 16) & 1u)) >> 16);
}
__device__ __forceinline__ float bf2f(unsigned short h) {
    return __uint_as_float(((unsigned int)h) << 16);
}

// M[n][t][t2] = sum_h ad[h][t]*ad[h][t2],  ad[h][t] = sum_k ne[n][k]*adj[k][h][t]
__global__ void k_prepM(const float* __restrict__ ne, const float* __restrict__ adj,
                        float* __restrict__ M) {
    __shared__ float s_ne[K_];
    __shared__ float s_ad[H_ * T_];
    const int n = blockIdx.x;
    const int tid = threadIdx.x;  // 64 threads
    if (tid < K_) s_ne[tid] = ne[n * K_ + tid];
    __syncthreads();
    for (int f = tid; f < H_ * T_; f += 64) {
        const int h = f / T_, t = f % T_;
        float a = 0.f;
#pragma unroll
        for (int k = 0; k < K_; ++k) a += s_ne[k] * adj[(k * H_ + h) * T_ + t];
        s_ad[f] = a;
    }
    __syncthreads();
    for (int m = tid; m < T_ * T_; m += 64) {
        const int t = m / T_, t2 = m % T_;
        float a = 0.f;
#pragma unroll
        for (int h = 0; h < H_; ++h) a += s_ad[h * T_ + t] * s_ad[h * T_ + t2];
        M[n * (T_ * T_) + m] = a;
    }
}

// Wt[bt][o][i] (bf16) = sum_k te[bt][k]*wp[k][i][o];  bias[bt][o] f32
__global__ __launch_bounds__(256) void k_prepW(const float* __restrict__ te,
                                               const float* __restrict__ wp,
                                               const float* __restrict__ bp,
                                               unsigned short* __restrict__ Wt,
                                               float* __restrict__ bias) {
    const int bt = blockIdx.x;   // 0..B*T-1
    const int tid = threadIdx.x; // 256
    __shared__ float s_te[K_];
    __shared__ float s_W[D_ * D_];  // [i][o] f32
    if (tid < K_) s_te[tid] = te[bt * K_ + tid];
    __syncthreads();
    float4 acc[4] = {};
    for (int k = 0; k < K_; ++k) {
        const float tk = s_te[k];
        const float4* row = (const float4*)(wp + (size_t)k * (D_ * D_));
#pragma unroll
        for (int i = 0; i < 4; ++i) {
            float4 v = row[tid + i * 256];
            acc[i].x += tk * v.x; acc[i].y += tk * v.y;
            acc[i].z += tk * v.z; acc[i].w += tk * v.w;
        }
    }
    float4* sW4 = (float4*)s_W;
#pragma unroll
    for (int i = 0; i < 4; ++i) sW4[tid + i * 256] = acc[i];
    if (tid < D_) {
        float a = 0.f;
#pragma unroll
        for (int k = 0; k < K_; ++k) a += s_te[k] * bp[k * D_ + tid];
        bias[bt * D_ + tid] = a;
    }
    __syncthreads();
    // transpose -> bf16: Wt[o][i]
    const int o = tid >> 2;
    const int i0 = (tid & 3) * 16;
    unsigned short* dst = Wt + (size_t)bt * (D_ * D_) + o * D_ + i0;
#pragma unroll
    for (int j = 0; j < 16; j += 4) {
        ushort4 u;
        u.x = f2bf(s_W[(i0 + j + 0) * D_ + o]);
        u.y = f2bf(s_W[(i0 + j + 1) * D_ + o]);
        u.z = f2bf(s_W[(i0 + j + 2) * D_ + o]);
        u.w = f2bf(s_W[(i0 + j + 3) * D_ + o]);
        *(ushort4*)(dst + j) = u;
    }
}

// Fused: ret = M-mix of eb (registers, MFMA-A-frag layout) -> MFMA vs Wt -> epilogue.
// Block = (16-node tile, b). eb slice staged once in LDS (bf16, XOR-swizzled).
// Wave w handles t in [w*6, w*6+6), two passes of 3 t's.
// M rows prefetched to registers (18 x float4) per pass -> no inner-loop gather.
__global__ __launch_bounds__(256, 3) void k_fused(const float* __restrict__ eb,
                                                  const float* __restrict__ M,
                                                  const unsigned short* __restrict__ Wt,
                                                  const float* __restrict__ bias,
                                                  float* __restrict__ out) {
    const int b = blockIdx.y;
    const int nb = blockIdx.x * NB;
    const int tid = threadIdx.x;
    const int wave = tid >> 6, lane = tid & 63;
    const int lr = lane & 15, lh = lane >> 4;

    __shared__ unsigned short s_eb[T_ * NB * D_]; // [t][n][d] bf16, row=128B, swizzled

    // ---- stage eb[b][:][nb:nb+16][:] -> LDS bf16 ----
    {
        const int n = tid >> 4;
        const int d0 = (tid & 15) * 4;
        const int inrow = (d0 * 2) ^ ((n & 7) << 4);
        char* dst0 = (char*)s_eb + n * 128 + inrow;
        const float* src = eb + ((size_t)(b * T_) * N_ + nb + n) * D_ + d0;
#pragma unroll 4
        for (int it = 0; it < T_; ++it) {
            const float4 v = *(const float4*)(src + (size_t)it * (N_ * D_));
            ushort4 u;
            u.x = f2bf(v.x); u.y = f2bf(v.y); u.z = f2bf(v.z); u.w = f2bf(v.w);
            *(ushort4*)(dst0 + it * (NB * 128)) = u;
        }
    }
    __syncthreads();

    const float* Mn = M + (size_t)(nb + lr) * (T_ * T_);
    const char* ebase = (const char*)s_eb;
    const int sw = (lr & 7) << 4;

    for (int pass = 0; pass < 2; ++pass) {
        const int tb = wave * 6 + pass * 3;

        // prefetch M[nb+lr][tb..tb+2][0..23] as 18 float4 (72 VGPR), one burst
        float4 mt4[3][6];
#pragma unroll
        for (int tt = 0; tt < 3; ++tt)
#pragma unroll
            for (int q = 0; q < 6; ++q)
                mt4[tt][q] = *(const float4*)(Mn + (tb + tt) * T_ + q * 4);

        float acc[3][16];
#pragma unroll
        for (int tt = 0; tt < 3; ++tt)
#pragma unroll
            for (int j = 0; j < 16; ++j) acc[tt][j] = 0.f;

#pragma unroll
        for (int tp = 0; tp < T_; ++tp) {
            const char* rowp = ebase + (tp * NB + lr) * 128;
            const bf16x8 e0 = *(const bf16x8*)(rowp + ((lh * 16) ^ sw));
            const bf16x8 e1 = *(const bf16x8*)(rowp + (((lh + 4) * 16) ^ sw));
            float ef[16];
#pragma unroll
            for (int j = 0; j < 8; ++j) {
                ef[j]     = bf2f((unsigned short)e0[j]);
                ef[8 + j] = bf2f((unsigned short)e1[j]);
            }
            const int q = tp >> 2, rm = tp & 3;
            const float m0 = ((const float*)&mt4[0][q])[rm];
            const float m1 = ((const float*)&mt4[1][q])[rm];
            const float m2 = ((const float*)&mt4[2][q])[rm];
#pragma unroll
            for (int j = 0; j < 16; ++j) {
                acc[0][j] += m0 * ef[j];
                acc[1][j] += m1 * ef[j];
                acc[2][j] += m2 * ef[j];
            }
        }

        // convert to MFMA A-fragments: lane holds ret[t][n=lr][lh*8+j] and [32+lh*8+j]
        bf16x8 Af[3][2];
#pragma unroll
        for (int tt = 0; tt < 3; ++tt)
#pragma unroll
            for (int j = 0; j < 8; ++j) {
                Af[tt][0][j] = (short)f2bf(acc[tt][j]);
                Af[tt][1][j] = (short)f2bf(acc[tt][8 + j]);
            }

#pragma unroll
        for (int tt = 0; tt < 3; ++tt) {
            const int t = tb + tt;
            const int bt = b * T_ + t;
            const unsigned short* Wb = Wt + (size_t)bt * (D_ * D_);
            f32x4 C[4] = {};
#pragma unroll
            for (int ot = 0; ot < 4; ++ot) {
                const bf16x8 B0 = *(const bf16x8*)(Wb + (ot * 16 + lr) * D_ + lh * 8);
                const bf16x8 B1 = *(const bf16x8*)(Wb + (ot * 16 + lr) * D_ + 32 + lh * 8);
                C[ot] = __builtin_amdgcn_mfma_f32_16x16x32_bf16(Af[tt][0], B0, C[ot], 0, 0, 0);
                C[ot] = __builtin_amdgcn_mfma_f32_16x16x32_bf16(Af[tt][1], B1, C[ot], 0, 0, 0);
            }
            float bv[4];
#pragma unroll
            for (int ot = 0; ot < 4; ++ot) bv[ot] = bias[bt * D_ + ot * 16 + lr];

            float* obt = out + ((size_t)bt * N_ + nb) * D_;
#pragma unroll
            for (int r = 0; r < 4; ++r) {
                const int nn = lh * 4 + r;  // node within tile (C-row)
                const char* erow = ebase + (t * NB + nn) * 128;
                const int swn = (nn & 7) << 4;
#pragma unroll
                for (int ot = 0; ot < 4; ++ot) {
                    const int o = ot * 16 + lr;  // C-col
                    const unsigned short eu =
                        *(const unsigned short*)(erow + ((o * 2) ^ swn));
                    float v = C[ot][r] + bv[ot] + bf2f(eu);
                    v = v >= 0.f ? v : 0.01f * v;
                    obt[(size_t)nn * D_ + o] = v;
                }
            }
        }
    }
}

extern "C" void kernel_launch(void* const* d_in, const int* in_sizes, int n_in,
                              void* d_out, int out_size, void* d_ws, size_t ws_size,
                              hipStream_t stream) {
    const float* eb  = (const float*)d_in[0];
    const float* ne  = (const float*)d_in[1];
    const float* te  = (const float*)d_in[2];
    const float* adj = (const float*)d_in[3];
    const float* wp  = (const float*)d_in[4];
    const float* bp  = (const float*)d_in[5];
    float* out = (float*)d_out;

    char* ws = (char*)d_ws;
    const size_t M_bytes  = (size_t)N_ * T_ * T_ * 4;       // 4,718,592
    const size_t Wt_bytes = (size_t)B_ * T_ * D_ * D_ * 2;  // 6,291,456
    float* M           = (float*)ws;
    unsigned short* Wt = (unsigned short*)(ws + M_bytes);
    float* bias        = (float*)(ws + M_bytes + Wt_bytes);

    k_prepM<<<N_, 64, 0, stream>>>(ne, adj, M);
    k_prepW<<<B_ * T_, 256, 0, stream>>>(te, wp, bp, Wt, bias);
    k_fused<<<dim3(N_ / NB, B_), 256, 0, stream>>>(eb, M, Wt, bias, out);
}

// Round 5
// 2729.780 us; speedup vs baseline: 1.0020x; 1.0020x over previous
//
#include <hip/hip_runtime.h>

#define B_ 32
#define T_ 24
#define N_ 2048
#define D_ 64
#define K_ 32
#define H_ 16
#define NB 16

typedef __attribute__((ext_vector_type(8))) short bf16x8;
typedef __attribute__((ext_vector_type(4))) float f32x4;

__device__ __forceinline__ unsigned short f2bf(float f) {
    unsigned int u = __float_as_uint(f);
    return (unsigned short)((u + 0x7FFFu + ((u >> 16) & 1u)) >> 16);
}
__device__ __forceinline__ float bf2f(unsigned short h) {
    return __uint_as_float(((unsigned int)h) << 16);
}

// M[n][t][t2] = sum_h ad[h][t]*ad[h][t2],  ad[h][t] = sum_k ne[n][k]*adj[k][h][t]
__global__ void k_prepM(const float* __restrict__ ne, const float* __restrict__ adj,
                        float* __restrict__ M) {
    __shared__ float s_ne[K_];
    __shared__ float s_ad[H_ * T_];
    const int n = blockIdx.x;
    const int tid = threadIdx.x;  // 64 threads
    if (tid < K_) s_ne[tid] = ne[n * K_ + tid];
    __syncthreads();
    for (int f = tid; f < H_ * T_; f += 64) {
        const int h = f / T_, t = f % T_;
        float a = 0.f;
#pragma unroll
        for (int k = 0; k < K_; ++k) a += s_ne[k] * adj[(k * H_ + h) * T_ + t];
        s_ad[f] = a;
    }
    __syncthreads();
    for (int m = tid; m < T_ * T_; m += 64) {
        const int t = m / T_, t2 = m % T_;
        float a = 0.f;
#pragma unroll
        for (int h = 0; h < H_; ++h) a += s_ad[h * T_ + t] * s_ad[h * T_ + t2];
        M[n * (T_ * T_) + m] = a;
    }
}

// Wt[bt][o][i] (bf16) = sum_k te[bt][k]*wp[k][i][o];  bias[bt][o] f32
__global__ __launch_bounds__(256) void k_prepW(const float* __restrict__ te,
                                               const float* __restrict__ wp,
                                               const float* __restrict__ bp,
                                               unsigned short* __restrict__ Wt,
                                               float* __restrict__ bias) {
    const int bt = blockIdx.x;   // 0..B*T-1
    const int tid = threadIdx.x; // 256
    __shared__ float s_te[K_];
    __shared__ float s_W[D_ * D_];  // [i][o] f32
    if (tid < K_) s_te[tid] = te[bt * K_ + tid];
    __syncthreads();
    float4 acc[4] = {};
    for (int k = 0; k < K_; ++k) {
        const float tk = s_te[k];
        const float4* row = (const float4*)(wp + (size_t)k * (D_ * D_));
#pragma unroll
        for (int i = 0; i < 4; ++i) {
            float4 v = row[tid + i * 256];
            acc[i].x += tk * v.x; acc[i].y += tk * v.y;
            acc[i].z += tk * v.z; acc[i].w += tk * v.w;
        }
    }
    float4* sW4 = (float4*)s_W;
#pragma unroll
    for (int i = 0; i < 4; ++i) sW4[tid + i * 256] = acc[i];
    if (tid < D_) {
        float a = 0.f;
#pragma unroll
        for (int k = 0; k < K_; ++k) a += s_te[k] * bp[k * D_ + tid];
        bias[bt * D_ + tid] = a;
    }
    __syncthreads();
    // transpose -> bf16: Wt[o][i]
    const int o = tid >> 2;
    const int i0 = (tid & 3) * 16;
    unsigned short* dst = Wt + (size_t)bt * (D_ * D_) + o * D_ + i0;
#pragma unroll
    for (int j = 0; j < 16; j += 4) {
        ushort4 u;
        u.x = f2bf(s_W[(i0 + j + 0) * D_ + o]);
        u.y = f2bf(s_W[(i0 + j + 1) * D_ + o]);
        u.z = f2bf(s_W[(i0 + j + 2) * D_ + o]);
        u.w = f2bf(s_W[(i0 + j + 3) * D_ + o]);
        *(ushort4*)(dst + j) = u;
    }
}

// Fused: ret = M-mix of eb (registers, MFMA-A-frag layout) -> MFMA vs Wt -> epilogue.
// Block = (16-node tile, b). eb slice staged once in LDS (bf16, XOR-swizzled).
// Wave w handles t in [w*6, w*6+6), two passes of 3 t's.
// M accessed as 3 x f32x4 per tp-quad, constant vector subscripts only (no scratch).
__global__ __launch_bounds__(256, 3) void k_fused(const float* __restrict__ eb,
                                                  const float* __restrict__ M,
                                                  const unsigned short* __restrict__ Wt,
                                                  const float* __restrict__ bias,
                                                  float* __restrict__ out) {
    const int b = blockIdx.y;
    const int nb = blockIdx.x * NB;
    const int tid = threadIdx.x;
    const int wave = tid >> 6, lane = tid & 63;
    const int lr = lane & 15, lh = lane >> 4;

    __shared__ unsigned short s_eb[T_ * NB * D_]; // [t][n][d] bf16, row=128B, swizzled

    // ---- stage eb[b][:][nb:nb+16][:] -> LDS bf16 ----
    {
        const int n = tid >> 4;
        const int d0 = (tid & 15) * 4;
        const int inrow = (d0 * 2) ^ ((n & 7) << 4);
        char* dst0 = (char*)s_eb + n * 128 + inrow;
        const float* src = eb + ((size_t)(b * T_) * N_ + nb + n) * D_ + d0;
#pragma unroll 4
        for (int it = 0; it < T_; ++it) {
            const float4 v = *(const float4*)(src + (size_t)it * (N_ * D_));
            ushort4 u;
            u.x = f2bf(v.x); u.y = f2bf(v.y); u.z = f2bf(v.z); u.w = f2bf(v.w);
            *(ushort4*)(dst0 + it * (NB * 128)) = u;
        }
    }
    __syncthreads();

    const float* Mn = M + (size_t)(nb + lr) * (T_ * T_);
    const char* ebase = (const char*)s_eb;
    const int sw = (lr & 7) << 4;

    for (int pass = 0; pass < 2; ++pass) {
        const int tb = wave * 6 + pass * 3;

        float acc[3][16];
#pragma unroll
        for (int tt = 0; tt < 3; ++tt)
#pragma unroll
            for (int j = 0; j < 16; ++j) acc[tt][j] = 0.f;

#pragma unroll
        for (int q = 0; q < 6; ++q) {
            // M rows tb..tb+2, quad q: three independent 16B L2 loads,
            // subscripted ONLY with constant r below (extractelement, no scratch)
            const f32x4 ma = *(const f32x4*)(Mn + (tb + 0) * T_ + q * 4);
            const f32x4 mb = *(const f32x4*)(Mn + (tb + 1) * T_ + q * 4);
            const f32x4 mc = *(const f32x4*)(Mn + (tb + 2) * T_ + q * 4);
#pragma unroll
            for (int r = 0; r < 4; ++r) {
                const int tp = q * 4 + r;
                const char* rowp = ebase + (tp * NB + lr) * 128;
                const bf16x8 e0 = *(const bf16x8*)(rowp + ((lh * 16) ^ sw));
                const bf16x8 e1 = *(const bf16x8*)(rowp + (((lh + 4) * 16) ^ sw));
                float ef[16];
#pragma unroll
                for (int j = 0; j < 8; ++j) {
                    ef[j]     = bf2f((unsigned short)e0[j]);
                    ef[8 + j] = bf2f((unsigned short)e1[j]);
                }
                const float m0 = ma[r], m1 = mb[r], m2 = mc[r];
#pragma unroll
                for (int j = 0; j < 16; ++j) {
                    acc[0][j] += m0 * ef[j];
                    acc[1][j] += m1 * ef[j];
                    acc[2][j] += m2 * ef[j];
                }
            }
        }

        // convert to MFMA A-fragments: lane holds ret[t][n=lr][lh*8+j] and [32+lh*8+j]
        bf16x8 Af[3][2];
#pragma unroll
        for (int tt = 0; tt < 3; ++tt)
#pragma unroll
            for (int j = 0; j < 8; ++j) {
                Af[tt][0][j] = (short)f2bf(acc[tt][j]);
                Af[tt][1][j] = (short)f2bf(acc[tt][8 + j]);
            }

#pragma unroll
        for (int tt = 0; tt < 3; ++tt) {
            const int t = tb + tt;
            const int bt = b * T_ + t;
            const unsigned short* Wb = Wt + (size_t)bt * (D_ * D_);
            f32x4 C[4] = {};
#pragma unroll
            for (int ot = 0; ot < 4; ++ot) {
                const bf16x8 B0 = *(const bf16x8*)(Wb + (ot * 16 + lr) * D_ + lh * 8);
                const bf16x8 B1 = *(const bf16x8*)(Wb + (ot * 16 + lr) * D_ + 32 + lh * 8);
                C[ot] = __builtin_amdgcn_mfma_f32_16x16x32_bf16(Af[tt][0], B0, C[ot], 0, 0, 0);
                C[ot] = __builtin_amdgcn_mfma_f32_16x16x32_bf16(Af[tt][1], B1, C[ot], 0, 0, 0);
            }
            float bv[4];
#pragma unroll
            for (int ot = 0; ot < 4; ++ot) bv[ot] = bias[bt * D_ + ot * 16 + lr];

            float* obt = out + ((size_t)bt * N_ + nb) * D_;
#pragma unroll
            for (int r = 0; r < 4; ++r) {
                const int nn = lh * 4 + r;  // node within tile (C-row)
                const char* erow = ebase + (t * NB + nn) * 128;
                const int swn = (nn & 7) << 4;
#pragma unroll
                for (int ot = 0; ot < 4; ++ot) {
                    const int o = ot * 16 + lr;  // C-col
                    const unsigned short eu =
                        *(const unsigned short*)(erow + ((o * 2) ^ swn));
                    float v = C[ot][r] + bv[ot] + bf2f(eu);
                    v = v >= 0.f ? v : 0.01f * v;
                    obt[(size_t)nn * D_ + o] = v;
                }
            }
        }
    }
}

extern "C" void kernel_launch(void* const* d_in, const int* in_sizes, int n_in,
                              void* d_out, int out_size, void* d_ws, size_t ws_size,
                              hipStream_t stream) {
    const float* eb  = (const float*)d_in[0];
    const float* ne  = (const float*)d_in[1];
    const float* te  = (const float*)d_in[2];
    const float* adj = (const float*)d_in[3];
    const float* wp  = (const float*)d_in[4];
    const float* bp  = (const float*)d_in[5];
    float* out = (float*)d_out;

    char* ws = (char*)d_ws;
    const size_t M_bytes  = (size_t)N_ * T_ * T_ * 4;       // 4,718,592
    const size_t Wt_bytes = (size_t)B_ * T_ * D_ * D_ * 2;  // 6,291,456
    float* M           = (float*)ws;
    unsigned short* Wt = (unsigned short*)(ws + M_bytes);
    float* bias        = (float*)(ws + M_bytes + Wt_bytes);

    k_prepM<<<N_, 64, 0, stream>>>(ne, adj, M);
    k_prepW<<<B_ * T_, 256, 0, stream>>>(te, wp, bp, Wt, bias);
    k_fused<<<dim3(N_ / NB, B_), 256, 0, stream>>>(eb, M, Wt, bias, out);
}

// Round 6
// 274.578 us; speedup vs baseline: 9.9614x; 9.9417x over previous
//
#include <hip/hip_runtime.h>

#define B_ 32
#define T_ 24
#define N_ 2048
#define D_ 64
#define K_ 32
#define H_ 16
#define NB 16

typedef __attribute__((ext_vector_type(8))) short bf16x8;
typedef __attribute__((ext_vector_type(4))) float f32x4;

__device__ __forceinline__ unsigned short f2bf(float f) {
    unsigned int u = __float_as_uint(f);
    return (unsigned short)((u + 0x7FFFu + ((u >> 16) & 1u)) >> 16);
}
__device__ __forceinline__ float bf2f(unsigned short h) {
    return __uint_as_float(((unsigned int)h) << 16);
}

// M2[n>>4][t][t2][n&15] = sum_h ad[h][t]*ad[h][t2],  ad[h][t] = sum_k ne[n][k]*adj[k][h][t]
// Lane-coalesced layout: 16 nodes of a block are adjacent in the last dim.
__global__ void k_prepM(const float* __restrict__ ne, const float* __restrict__ adj,
                        float* __restrict__ M2) {
    __shared__ float s_ne[K_];
    __shared__ float s_ad[H_ * T_];
    const int n = blockIdx.x;
    const int tid = threadIdx.x;  // 64 threads
    if (tid < K_) s_ne[tid] = ne[n * K_ + tid];
    __syncthreads();
    for (int f = tid; f < H_ * T_; f += 64) {
        const int h = f / T_, t = f % T_;
        float a = 0.f;
#pragma unroll
        for (int k = 0; k < K_; ++k) a += s_ne[k] * adj[(k * H_ + h) * T_ + t];
        s_ad[f] = a;
    }
    __syncthreads();
    float* dst = M2 + (size_t)(n >> 4) * (T_ * T_ * 16) + (n & 15);
    for (int m = tid; m < T_ * T_; m += 64) {
        const int t = m / T_, t2 = m % T_;
        float a = 0.f;
#pragma unroll
        for (int h = 0; h < H_; ++h) a += s_ad[h * T_ + t] * s_ad[h * T_ + t2];
        dst[m * 16] = a;
    }
}

// Wt[bt][o][i] (bf16) = sum_k te[bt][k]*wp[k][i][o];  bias[bt][o] f32
__global__ __launch_bounds__(256) void k_prepW(const float* __restrict__ te,
                                               const float* __restrict__ wp,
                                               const float* __restrict__ bp,
                                               unsigned short* __restrict__ Wt,
                                               float* __restrict__ bias) {
    const int bt = blockIdx.x;   // 0..B*T-1
    const int tid = threadIdx.x; // 256
    __shared__ float s_te[K_];
    __shared__ float s_W[D_ * D_];  // [i][o] f32
    if (tid < K_) s_te[tid] = te[bt * K_ + tid];
    __syncthreads();
    float4 acc[4] = {};
    for (int k = 0; k < K_; ++k) {
        const float tk = s_te[k];
        const float4* row = (const float4*)(wp + (size_t)k * (D_ * D_));
#pragma unroll
        for (int i = 0; i < 4; ++i) {
            float4 v = row[tid + i * 256];
            acc[i].x += tk * v.x; acc[i].y += tk * v.y;
            acc[i].z += tk * v.z; acc[i].w += tk * v.w;
        }
    }
    float4* sW4 = (float4*)s_W;
#pragma unroll
    for (int i = 0; i < 4; ++i) sW4[tid + i * 256] = acc[i];
    if (tid < D_) {
        float a = 0.f;
#pragma unroll
        for (int k = 0; k < K_; ++k) a += s_te[k] * bp[k * D_ + tid];
        bias[bt * D_ + tid] = a;
    }
    __syncthreads();
    // transpose -> bf16: Wt[o][i]
    const int o = tid >> 2;
    const int i0 = (tid & 3) * 16;
    unsigned short* dst = Wt + (size_t)bt * (D_ * D_) + o * D_ + i0;
#pragma unroll
    for (int j = 0; j < 16; j += 4) {
        ushort4 u;
        u.x = f2bf(s_W[(i0 + j + 0) * D_ + o]);
        u.y = f2bf(s_W[(i0 + j + 1) * D_ + o]);
        u.z = f2bf(s_W[(i0 + j + 2) * D_ + o]);
        u.w = f2bf(s_W[(i0 + j + 3) * D_ + o]);
        *(ushort4*)(dst + j) = u;
    }
}

// Fused: ret = M-mix of eb (registers, MFMA-A-frag layout) -> MFMA vs Wt -> epilogue.
// Block = (16-node tile, b). eb slice staged once in LDS (bf16, XOR-swizzled).
// Wave w handles t in [w*6, w*6+6), two passes of 3 t's.
// M loads are 3 scalar loads/tp from M2's lane-coalesced layout (1 L2 line per wave-load).
__global__ __launch_bounds__(256, 3) void k_fused(const float* __restrict__ eb,
                                                  const float* __restrict__ M2,
                                                  const unsigned short* __restrict__ Wt,
                                                  const float* __restrict__ bias,
                                                  float* __restrict__ out) {
    const int b = blockIdx.y;
    const int nb = blockIdx.x * NB;
    const int tid = threadIdx.x;
    const int wave = tid >> 6, lane = tid & 63;
    const int lr = lane & 15, lh = lane >> 4;

    __shared__ unsigned short s_eb[T_ * NB * D_]; // [t][n][d] bf16, row=128B, swizzled

    // ---- stage eb[b][:][nb:nb+16][:] -> LDS bf16 ----
    {
        const int n = tid >> 4;
        const int d0 = (tid & 15) * 4;
        const int inrow = (d0 * 2) ^ ((n & 7) << 4);
        char* dst0 = (char*)s_eb + n * 128 + inrow;
        const float* src = eb + ((size_t)(b * T_) * N_ + nb + n) * D_ + d0;
#pragma unroll 4
        for (int it = 0; it < T_; ++it) {
            const float4 v = *(const float4*)(src + (size_t)it * (N_ * D_));
            ushort4 u;
            u.x = f2bf(v.x); u.y = f2bf(v.y); u.z = f2bf(v.z); u.w = f2bf(v.w);
            *(ushort4*)(dst0 + it * (NB * 128)) = u;
        }
    }
    __syncthreads();

    // lane's M base: node nb+lr -> block slice [blockIdx.x][t][tp][lr]
    const float* Mblk = M2 + (size_t)blockIdx.x * (T_ * T_ * 16) + lr;
    const char* ebase = (const char*)s_eb;
    const int sw = (lr & 7) << 4;

    for (int pass = 0; pass < 2; ++pass) {
        const int tb = wave * 6 + pass * 3;
        float acc[3][16];
#pragma unroll
        for (int tt = 0; tt < 3; ++tt)
#pragma unroll
            for (int j = 0; j < 16; ++j) acc[tt][j] = 0.f;

#pragma unroll 4
        for (int tp = 0; tp < T_; ++tp) {
            const float* mcol = Mblk + ((size_t)tb * T_ + tp) * 16;
            const float m0 = mcol[0 * T_ * 16];
            const float m1 = mcol[1 * T_ * 16];
            const float m2 = mcol[2 * T_ * 16];
            const char* rowp = ebase + (tp * NB + lr) * 128;
            const bf16x8 e0 = *(const bf16x8*)(rowp + ((lh * 16) ^ sw));
            const bf16x8 e1 = *(const bf16x8*)(rowp + (((lh + 4) * 16) ^ sw));
            float ef[16];
#pragma unroll
            for (int j = 0; j < 8; ++j) {
                ef[j]     = bf2f((unsigned short)e0[j]);
                ef[8 + j] = bf2f((unsigned short)e1[j]);
            }
#pragma unroll
            for (int j = 0; j < 16; ++j) {
                acc[0][j] += m0 * ef[j];
                acc[1][j] += m1 * ef[j];
                acc[2][j] += m2 * ef[j];
            }
        }

        // convert to MFMA A-fragments: lane holds ret[t][n=lr][lh*8+j] and [32+lh*8+j]
        bf16x8 Af[3][2];
#pragma unroll
        for (int tt = 0; tt < 3; ++tt)
#pragma unroll
            for (int j = 0; j < 8; ++j) {
                Af[tt][0][j] = (short)f2bf(acc[tt][j]);
                Af[tt][1][j] = (short)f2bf(acc[tt][8 + j]);
            }

#pragma unroll
        for (int tt = 0; tt < 3; ++tt) {
            const int t = tb + tt;
            const int bt = b * T_ + t;
            const unsigned short* Wb = Wt + (size_t)bt * (D_ * D_);
            f32x4 C[4] = {};
#pragma unroll
            for (int ot = 0; ot < 4; ++ot) {
                const bf16x8 B0 = *(const bf16x8*)(Wb + (ot * 16 + lr) * D_ + lh * 8);
                const bf16x8 B1 = *(const bf16x8*)(Wb + (ot * 16 + lr) * D_ + 32 + lh * 8);
                C[ot] = __builtin_amdgcn_mfma_f32_16x16x32_bf16(Af[tt][0], B0, C[ot], 0, 0, 0);
                C[ot] = __builtin_amdgcn_mfma_f32_16x16x32_bf16(Af[tt][1], B1, C[ot], 0, 0, 0);
            }
            float bv[4];
#pragma unroll
            for (int ot = 0; ot < 4; ++ot) bv[ot] = bias[bt * D_ + ot * 16 + lr];

            float* obt = out + ((size_t)bt * N_ + nb) * D_;
#pragma unroll
            for (int r = 0; r < 4; ++r) {
                const int nn = lh * 4 + r;  // node within tile (C-row)
                const char* erow = ebase + (t * NB + nn) * 128;
                const int swn = (nn & 7) << 4;
#pragma unroll
                for (int ot = 0; ot < 4; ++ot) {
                    const int o = ot * 16 + lr;  // C-col
                    const unsigned short eu =
                        *(const unsigned short*)(erow + ((o * 2) ^ swn));
                    float v = C[ot][r] + bv[ot] + bf2f(eu);
                    v = v >= 0.f ? v : 0.01f * v;
                    obt[(size_t)nn * D_ + o] = v;
                }
            }
        }
    }
}

extern "C" void kernel_launch(void* const* d_in, const int* in_sizes, int n_in,
                              void* d_out, int out_size, void* d_ws, size_t ws_size,
                              hipStream_t stream) {
    const float* eb  = (const float*)d_in[0];
    const float* ne  = (const float*)d_in[1];
    const float* te  = (const float*)d_in[2];
    const float* adj = (const float*)d_in[3];
    const float* wp  = (const float*)d_in[4];
    const float* bp  = (const float*)d_in[5];
    float* out = (float*)d_out;

    char* ws = (char*)d_ws;
    const size_t M_bytes  = (size_t)N_ * T_ * T_ * 4;       // 4,718,592
    const size_t Wt_bytes = (size_t)B_ * T_ * D_ * D_ * 2;  // 6,291,456
    float* M2          = (float*)ws;
    unsigned short* Wt = (unsigned short*)(ws + M_bytes);
    float* bias        = (float*)(ws + M_bytes + Wt_bytes);

    k_prepM<<<N_, 64, 0, stream>>>(ne, adj, M2);
    k_prepW<<<B_ * T_, 256, 0, stream>>>(te, wp, bp, Wt, bias);
    k_fused<<<dim3(N_ / NB, B_), 256, 0, stream>>>(eb, M2, Wt, bias, out);
}